// Round 6
// baseline (653.069 us; speedup 1.0000x reference)
//
#include <hip/hip_runtime.h>

#define NQ    10
#define NPRM  100
#define NBATCH 8192

using F2 = float2;

__device__ __forceinline__ float shflx(float v, int m) { return __shfl_xor(v, m, 64); }

// Amplitude index i (10 bits): bits 0..3 = per-lane register index r, bits 4..9 = lane id.
// Wire w corresponds to global bit P = 9 - w (wire 0 = MSB, PennyLane order).

// ---------------- RX (used by CRX) ----------------

template<int P>
__device__ __forceinline__ void g_rx(F2* st, unsigned lane, float c, float s) {
  // RX: new0 = c*a0 - i s*a1 ; new1 = -i s*a0 + c*a1
  if constexpr (P < 4) {
    constexpr int m = 1 << P;
#pragma unroll
    for (int r = 0; r < 16; ++r) if (!(r & m)) {
      const int r1 = r | m;
      F2 a0 = st[r], a1 = st[r1];
      st[r]  = F2{c*a0.x + s*a1.y, c*a0.y - s*a1.x};
      st[r1] = F2{s*a0.y + c*a1.x, c*a1.y - s*a0.x};
    }
  } else {
    constexpr int lm = 1 << (P - 4);
#pragma unroll
    for (int r = 0; r < 16; ++r) {
      float mx = st[r].x, my = st[r].y;
      float ox = shflx(mx, lm), oy = shflx(my, lm);
      st[r] = F2{c*mx + s*oy, c*my - s*ox};   // same formula both sides (RX symmetry)
    }
  }
}

// ---------------- fused SU(2) gate: U = RZ*RY*RX, u11=conj(u00), u10=-conj(u01) ----------------

template<int P>
__device__ __forceinline__ void g_u(F2* st, unsigned lane, F2 u00, F2 u01) {
  if constexpr (P < 4) {
    constexpr int m = 1 << P;
#pragma unroll
    for (int r = 0; r < 16; ++r) if (!(r & m)) {
      const int r1 = r | m;
      F2 a0 = st[r], a1 = st[r1];
      st[r]  = F2{u00.x*a0.x - u00.y*a0.y + u01.x*a1.x - u01.y*a1.y,
                  u00.x*a0.y + u00.y*a0.x + u01.x*a1.y + u01.y*a1.x};
      st[r1] = F2{-u01.x*a0.x - u01.y*a0.y + u00.x*a1.x + u00.y*a1.y,
                  -u01.x*a0.y + u01.y*a0.x + u00.x*a1.y - u00.y*a1.x};
    }
  } else {
    constexpr int lm = 1 << (P - 4);
    const bool hi = (lane & lm) != 0;
    // my coefficient va = hi ? conj(u00) : u00 ; other coefficient vb = hi ? -conj(u01) : u01
    const float vax = u00.x,               vay = hi ? -u00.y : u00.y;
    const float vbx = hi ? -u01.x : u01.x, vby = u01.y;
#pragma unroll
    for (int r = 0; r < 16; ++r) {
      float mx = st[r].x, my = st[r].y;
      float ox = shflx(mx, lm), oy = shflx(my, lm);
      st[r] = F2{vax*mx - vay*my + vbx*ox - vby*oy,
                 vax*my + vay*mx + vbx*oy + vby*ox};
    }
  }
}

// ---------------- CRX ----------------

template<int TB, int CB>   // target bit, control bit
__device__ __forceinline__ void g_crx(F2* st, unsigned lane, float c, float s) {
  if constexpr (CB >= 4) {
    const bool act = (lane >> (CB - 4)) & 1u;
    const float ce = act ? c : 1.0f;
    const float se = act ? s : 0.0f;
    g_rx<TB>(st, lane, ce, se);
  } else {
    constexpr int cm = 1 << CB;
    if constexpr (TB < 4) {
#pragma unroll
      for (int r = 0; r < 16; ++r) if ((r & cm) && !(r & (1 << TB))) {
        const int r1 = r | (1 << TB);
        F2 a0 = st[r], a1 = st[r1];
        st[r]  = F2{c*a0.x + s*a1.y, c*a0.y - s*a1.x};
        st[r1] = F2{s*a0.y + c*a1.x, c*a1.y - s*a0.x};
      }
    } else {
      constexpr int lm = 1 << (TB - 4);
#pragma unroll
      for (int r = 0; r < 16; ++r) if (r & cm) {   // compile-time predicate
        float mx = st[r].x, my = st[r].y;
        float ox = shflx(mx, lm), oy = shflx(my, lm);
        st[r] = F2{c*mx + s*oy, c*my - s*ox};
      }
    }
  }
}

// ---------------- wire dispatch ----------------

__device__ __forceinline__ void g_u_w(F2* st, unsigned lane, int w, F2 u00, F2 u01) {
  switch (w) {
    case 0: g_u<9>(st,lane,u00,u01); break;
    case 1: g_u<8>(st,lane,u00,u01); break;
    case 2: g_u<7>(st,lane,u00,u01); break;
    case 3: g_u<6>(st,lane,u00,u01); break;
    case 4: g_u<5>(st,lane,u00,u01); break;
    case 5: g_u<4>(st,lane,u00,u01); break;
    case 6: g_u<3>(st,lane,u00,u01); break;
    case 7: g_u<2>(st,lane,u00,u01); break;
    case 8: g_u<1>(st,lane,u00,u01); break;
    case 9: g_u<0>(st,lane,u00,u01); break;
  }
}

#define CRX_CASE(CW,TW) case (CW)*10+(TW): g_crx<9-(TW), 9-(CW)>(st,lane,c,s); break;
__device__ __forceinline__ void crx_w(F2* st, unsigned lane, int cw, int tw, float c, float s) {
  switch (cw * 10 + tw) {
    CRX_CASE(0,1) CRX_CASE(1,2) CRX_CASE(2,3) CRX_CASE(3,4) CRX_CASE(4,5)
    CRX_CASE(5,6) CRX_CASE(6,7) CRX_CASE(7,8) CRX_CASE(8,9) CRX_CASE(9,0)
    CRX_CASE(1,0) CRX_CASE(2,1) CRX_CASE(3,2) CRX_CASE(4,3) CRX_CASE(5,4)
    CRX_CASE(6,5) CRX_CASE(7,6) CRX_CASE(8,7) CRX_CASE(9,8) CRX_CASE(0,9)
  }
}

// U = RZ(az)*RY(ay)*RX(ax) (half-angles inside); SU(2): only u00,u01 needed
__device__ __forceinline__ void make_u(float ax, float ay, float az, F2& u00, F2& u01) {
  float ca, sa, cb, sb, cg, sg;
  __sincosf(ax*0.5f, &sa, &ca);
  __sincosf(ay*0.5f, &sb, &cb);
  __sincosf(az*0.5f, &sg, &cg);
  const float m00x =  cb*ca, m00y =  sb*sa;
  const float m01x = -sb*ca, m01y = -cb*sa;
  u00 = F2{m00x*cg + m00y*sg, m00y*cg - m00x*sg};
  u01 = F2{m01x*cg + m01y*sg, m01y*cg - m01x*sg};
}

// ---------------- circuit layers ----------------

__device__ __forceinline__ void layer_fwd(F2* st, unsigned lane, const float* P, float dt, int& off) {
#pragma unroll
  for (int i = 0; i < NQ; ++i) {
    F2 u00, u01;
    make_u(P[off]*dt, P[off+1]*dt, P[off+2]*dt, u00, u01);
    g_u_w(st, lane, i, u00, u01);
    off += 3;
  }
#pragma unroll
  for (int i = 0; i < NQ; ++i) {
    float s, c; __sincosf(P[off]*0.5f, &s, &c);
    crx_w(st, lane, i, (i+1)%NQ, c, s); ++off;
  }
#pragma unroll
  for (int i = NQ-1; i >= 0; --i) {
    float s, c; __sincosf(P[off]*0.5f, &s, &c);
    crx_w(st, lane, i, (i+NQ-1)%NQ, c, s); ++off;
  }
}

__device__ __forceinline__ void layer_bwd(F2* st, unsigned lane, const float* P, float dt, int& off) {
#pragma unroll
  for (int i = NQ-1; i >= 0; --i) {
    F2 u00, u01;
    make_u(P[off]*dt, P[off+1]*dt, P[off+2]*dt, u00, u01);
    g_u_w(st, lane, i, u00, u01);
    off += 3;
  }
#pragma unroll
  for (int i = NQ-1; i >= 0; --i) {
    float s, c; __sincosf(P[off]*0.5f, &s, &c);
    crx_w(st, lane, i, (i+NQ-1)%NQ, c, s); ++off;
  }
#pragma unroll
  for (int i = 0; i < NQ; ++i) {
    float s, c; __sincosf(P[off]*0.5f, &s, &c);
    crx_w(st, lane, i, (i+1)%NQ, c, s); ++off;
  }
}

// RY-embedded |0..0> is a product state: amp(i) = prod_w (bit_w ? sin : cos)(ang_w/2)
__device__ __forceinline__ void init_state(F2* st, unsigned lane, const float* ang) {
  float cw[NQ], sw[NQ];
#pragma unroll
  for (int w = 0; w < NQ; ++w) __sincosf(ang[w]*0.5f, &sw[w], &cw[w]);
  float L = 1.0f;
#pragma unroll
  for (int q = 0; q < 6; ++q)            // lane bit q <-> wire 5-q
    L *= ((lane >> q) & 1u) ? sw[5-q] : cw[5-q];
#pragma unroll
  for (int r = 0; r < 16; ++r) {
    float R = L;
#pragma unroll
    for (int p = 0; p < 4; ++p)          // reg bit p <-> wire 9-p
      R *= ((r >> p) & 1) ? sw[9-p] : cw[9-p];
    st[r] = F2{R, 0.0f};
  }
}

// ---------------- measurement (on UNNORMALIZED state; caller scales by s^2) ----------------

template<int P>
__device__ __forceinline__ void meas(const F2* st, unsigned lane, float& X, float& Y, float& Z) {
  float cr = 0.f, ci = 0.f, z = 0.f;
  if constexpr (P < 4) {
    constexpr int m = 1 << P;
#pragma unroll
    for (int r = 0; r < 16; ++r) if (!(r & m)) {
      const int r1 = r | m;
      F2 a0 = st[r], a1 = st[r1];
      cr += a0.x*a1.x + a0.y*a1.y;
      ci += a0.x*a1.y - a0.y*a1.x;
      z  += (a0.x*a0.x + a0.y*a0.y) - (a1.x*a1.x + a1.y*a1.y);
    }
    cr *= 2.f; ci *= 2.f;
  } else {
    constexpr int lm = 1 << (P - 4);
    const bool hi = (lane & lm) != 0;
#pragma unroll
    for (int r = 0; r < 16; ++r) {
      float mx = st[r].x, my = st[r].y;
      float ox = shflx(mx, lm), oy = shflx(my, lm);
      float a0x = hi ? ox : mx, a0y = hi ? oy : my;
      float a1x = hi ? mx : ox, a1y = hi ? my : oy;
      cr += a0x*a1x + a0y*a1y;            // pair counted twice across lanes -> no *2
      ci += a0x*a1y - a0y*a1x;
      float p2 = mx*mx + my*my;
      z += hi ? -p2 : p2;
    }
  }
  X = cr; Y = ci; Z = z;
}

__device__ __forceinline__ float wred(float v) {
#pragma unroll
  for (int m = 1; m < 64; m <<= 1) v += shflx(v, m);
  return v;
}

// ---------------- kernel: one wave per batch element; circuit accumulator in wave-private LDS ----------------
// acc[16] in registers cost 32 VGPRs and pushed R3 to VGPR=72, just past the 64-reg
// occupancy step (m69: waves/SIMD halve at 64/128). Moving acc to LDS (8KB/wave,
// no barriers needed) targets VGPR<=64 -> 8 waves/SIMD by regs; LDS caps 20 waves/CU.

__global__ void __launch_bounds__(256) qsim_kernel(
    const float* __restrict__ angles, const float* __restrict__ fwdP,
    const float* __restrict__ bwdP,   const float* __restrict__ diagP,
    const float* __restrict__ dts,
    const float* __restrict__ ar, const float* __restrict__ ai,
    const float* __restrict__ br, const float* __restrict__ bi,
    const float* __restrict__ gr, const float* __restrict__ gi,
    float* __restrict__ out)
{
  __shared__ F2 accb[4][16][64];   // wave-private accumulators: 32 KB/block

  const int wave = threadIdx.x >> 6;
  const unsigned lane = threadIdx.x & 63u;
  const int b = blockIdx.x * 4 + wave;
  const int bu = __builtin_amdgcn_readfirstlane(b);

  F2 (*acc)[64] = accb[wave];

  const float* ang = angles + bu * NQ;
  const float dt = dts[bu];

  const float arv = ar[0], aiv = ai[0], brv = br[0], biv = bi[0], grv = gr[0], giv = gi[0];
  const float nrm = sqrtf(arv*arv + aiv*aiv + brv*brv + biv*biv + grv*grv + giv*giv + 1e-9f);
  const F2 cA{arv/nrm, aiv/nrm}, cB{brv/nrm, biv/nrm}, cG{grv/nrm, giv/nrm};

  F2 st[16];

  // circuit 1: forward (params scaled by dt) -> acc = cA * psi1
  init_state(st, lane, ang);
  { int off = 0; const float* P = fwdP + bu*NPRM;
#pragma unroll
    for (int l = 0; l < 2; ++l) layer_fwd(st, lane, P, dt, off); }
#pragma unroll
  for (int r = 0; r < 16; ++r)
    acc[r][lane] = F2{cA.x*st[r].x - cA.y*st[r].y, cA.x*st[r].y + cA.y*st[r].x};

  // circuit 2: backward -> acc += cB * psi2
  init_state(st, lane, ang);
  { int off = 0; const float* P = bwdP + bu*NPRM;
#pragma unroll
    for (int l = 0; l < 2; ++l) layer_bwd(st, lane, P, dt, off); }
#pragma unroll
  for (int r = 0; r < 16; ++r) {
    F2 t = acc[r][lane];
    t.x += cB.x*st[r].x - cB.y*st[r].y;
    t.y += cB.x*st[r].y + cB.y*st[r].x;
    acc[r][lane] = t;
  }

  // circuit 3: diagonal (forward structure, dt = 1) -> st = cG * psi3 + acc
  init_state(st, lane, ang);
  { int off = 0; const float* P = diagP + bu*NPRM;
#pragma unroll
    for (int l = 0; l < 2; ++l) layer_fwd(st, lane, P, 1.0f, off); }
#pragma unroll
  for (int r = 0; r < 16; ++r) {
    F2 t = acc[r][lane];
    st[r] = F2{cG.x*st[r].x - cG.y*st[r].y + t.x,
               cG.x*st[r].y + cG.y*st[r].x + t.y};
  }

  // deferred normalization: outputs are quadratic -> scale by s^2 at the end
  float n2 = 0.f;
#pragma unroll
  for (int r = 0; r < 16; ++r) n2 += st[r].x*st[r].x + st[r].y*st[r].y;
  n2 = wred(n2);
  const float s1 = 1.0f / (sqrtf(n2) + 1e-9f);
  const float s2 = s1 * s1;

  // measure X/Y/Z per wire (unnormalized), scale on write
  float* o = out + b * 30;
#pragma unroll
  for (int w = 0; w < NQ; ++w) {
    float X, Y, Z;
    switch (w) {
      case 0: meas<9>(st, lane, X, Y, Z); break;
      case 1: meas<8>(st, lane, X, Y, Z); break;
      case 2: meas<7>(st, lane, X, Y, Z); break;
      case 3: meas<6>(st, lane, X, Y, Z); break;
      case 4: meas<5>(st, lane, X, Y, Z); break;
      case 5: meas<4>(st, lane, X, Y, Z); break;
      case 6: meas<3>(st, lane, X, Y, Z); break;
      case 7: meas<2>(st, lane, X, Y, Z); break;
      case 8: meas<1>(st, lane, X, Y, Z); break;
      default: meas<0>(st, lane, X, Y, Z); break;
    }
    X = wred(X); Y = wred(Y); Z = wred(Z);
    if (lane == 0) { o[w] = X*s2; o[10 + w] = Y*s2; o[20 + w] = Z*s2; }
  }
}

extern "C" void kernel_launch(void* const* d_in, const int* in_sizes, int n_in,
                              void* d_out, int out_size, void* d_ws, size_t ws_size,
                              hipStream_t stream) {
  const float* angles = (const float*)d_in[0];
  const float* fwdP   = (const float*)d_in[1];
  const float* bwdP   = (const float*)d_in[2];
  const float* diagP  = (const float*)d_in[3];
  const float* dts    = (const float*)d_in[4];
  const float* ar     = (const float*)d_in[5];
  const float* ai     = (const float*)d_in[6];
  const float* br     = (const float*)d_in[7];
  const float* bi     = (const float*)d_in[8];
  const float* gr     = (const float*)d_in[9];
  const float* gi     = (const float*)d_in[10];
  float* out = (float*)d_out;

  const int threads = 256;                       // 4 waves/block, 1 batch elem/wave
  const int blocks  = NBATCH / (threads / 64);   // 2048
  qsim_kernel<<<blocks, threads, 0, stream>>>(
      angles, fwdP, bwdP, diagP, dts, ar, ai, br, bi, gr, gi, out);
}

// Round 7
// 257.278 us; speedup vs baseline: 2.5384x; 2.5384x over previous
//
#include <hip/hip_runtime.h>

#define NQ    10
#define NPRM  100
#define NBATCH 8192

using F2 = float2;

// Cross-lane XOR exchange. Masks 1,2,8 use DPP on the VALU pipe (latency ~4cyc,
// no LDS round-trip); masks 4,16,32 stay on ds_swizzle via __shfl_xor.
//  xor1 = quad_perm [1,0,3,2] = 0xB1 ; xor2 = quad_perm [2,3,0,1] = 0x4E
//  xor8 = row_ror:8 (0x128)  — (i+8)%16 == i^8, orientation-independent.
template<int LM>
__device__ __forceinline__ float lshf(float v) {
  if constexpr (LM == 1) {
    int r = __builtin_amdgcn_update_dpp(0, __builtin_bit_cast(int, v), 0xB1, 0xF, 0xF, true);
    return __builtin_bit_cast(float, r);
  } else if constexpr (LM == 2) {
    int r = __builtin_amdgcn_update_dpp(0, __builtin_bit_cast(int, v), 0x4E, 0xF, 0xF, true);
    return __builtin_bit_cast(float, r);
  } else if constexpr (LM == 8) {
    int r = __builtin_amdgcn_update_dpp(0, __builtin_bit_cast(int, v), 0x128, 0xF, 0xF, true);
    return __builtin_bit_cast(float, r);
  } else {
    return __shfl_xor(v, LM, 64);
  }
}

// Amplitude index i (10 bits): bits 0..3 = per-lane register index r, bits 4..9 = lane id.
// Wire w corresponds to global bit P = 9 - w (wire 0 = MSB, PennyLane order).

// ---------------- RX (used by CRX) ----------------

template<int P>
__device__ __forceinline__ void g_rx(F2* st, unsigned lane, float c, float s) {
  // RX: new0 = c*a0 - i s*a1 ; new1 = -i s*a0 + c*a1
  if constexpr (P < 4) {
    constexpr int m = 1 << P;
#pragma unroll
    for (int r = 0; r < 16; ++r) if (!(r & m)) {
      const int r1 = r | m;
      F2 a0 = st[r], a1 = st[r1];
      st[r]  = F2{c*a0.x + s*a1.y, c*a0.y - s*a1.x};
      st[r1] = F2{s*a0.y + c*a1.x, c*a1.y - s*a0.x};
    }
  } else {
    constexpr int lm = 1 << (P - 4);
#pragma unroll
    for (int r = 0; r < 16; ++r) {
      float mx = st[r].x, my = st[r].y;
      float ox = lshf<lm>(mx), oy = lshf<lm>(my);
      st[r] = F2{c*mx + s*oy, c*my - s*ox};   // same formula both sides (RX symmetry)
    }
  }
}

// ---------------- fused SU(2) gate: U = RZ*RY*RX, u11=conj(u00), u10=-conj(u01) ----------------

template<int P>
__device__ __forceinline__ void g_u(F2* st, unsigned lane, F2 u00, F2 u01) {
  if constexpr (P < 4) {
    constexpr int m = 1 << P;
#pragma unroll
    for (int r = 0; r < 16; ++r) if (!(r & m)) {
      const int r1 = r | m;
      F2 a0 = st[r], a1 = st[r1];
      st[r]  = F2{u00.x*a0.x - u00.y*a0.y + u01.x*a1.x - u01.y*a1.y,
                  u00.x*a0.y + u00.y*a0.x + u01.x*a1.y + u01.y*a1.x};
      st[r1] = F2{-u01.x*a0.x - u01.y*a0.y + u00.x*a1.x + u00.y*a1.y,
                  -u01.x*a0.y + u01.y*a0.x + u00.x*a1.y - u00.y*a1.x};
    }
  } else {
    constexpr int lm = 1 << (P - 4);
    const bool hi = (lane & lm) != 0;
    // my coefficient va = hi ? conj(u00) : u00 ; other coefficient vb = hi ? -conj(u01) : u01
    const float vax = u00.x,               vay = hi ? -u00.y : u00.y;
    const float vbx = hi ? -u01.x : u01.x, vby = u01.y;
#pragma unroll
    for (int r = 0; r < 16; ++r) {
      float mx = st[r].x, my = st[r].y;
      float ox = lshf<lm>(mx), oy = lshf<lm>(my);
      st[r] = F2{vax*mx - vay*my + vbx*ox - vby*oy,
                 vax*my + vay*mx + vbx*oy + vby*ox};
    }
  }
}

// ---------------- CRX ----------------

template<int TB, int CB>   // target bit, control bit
__device__ __forceinline__ void g_crx(F2* st, unsigned lane, float c, float s) {
  if constexpr (CB >= 4) {
    const bool act = (lane >> (CB - 4)) & 1u;
    const float ce = act ? c : 1.0f;
    const float se = act ? s : 0.0f;
    g_rx<TB>(st, lane, ce, se);
  } else {
    constexpr int cm = 1 << CB;
    if constexpr (TB < 4) {
#pragma unroll
      for (int r = 0; r < 16; ++r) if ((r & cm) && !(r & (1 << TB))) {
        const int r1 = r | (1 << TB);
        F2 a0 = st[r], a1 = st[r1];
        st[r]  = F2{c*a0.x + s*a1.y, c*a0.y - s*a1.x};
        st[r1] = F2{s*a0.y + c*a1.x, c*a1.y - s*a0.x};
      }
    } else {
      constexpr int lm = 1 << (TB - 4);
#pragma unroll
      for (int r = 0; r < 16; ++r) if (r & cm) {   // compile-time predicate
        float mx = st[r].x, my = st[r].y;
        float ox = lshf<lm>(mx), oy = lshf<lm>(my);
        st[r] = F2{c*mx + s*oy, c*my - s*ox};
      }
    }
  }
}

// ---------------- wire dispatch ----------------

__device__ __forceinline__ void g_u_w(F2* st, unsigned lane, int w, F2 u00, F2 u01) {
  switch (w) {
    case 0: g_u<9>(st,lane,u00,u01); break;
    case 1: g_u<8>(st,lane,u00,u01); break;
    case 2: g_u<7>(st,lane,u00,u01); break;
    case 3: g_u<6>(st,lane,u00,u01); break;
    case 4: g_u<5>(st,lane,u00,u01); break;
    case 5: g_u<4>(st,lane,u00,u01); break;
    case 6: g_u<3>(st,lane,u00,u01); break;
    case 7: g_u<2>(st,lane,u00,u01); break;
    case 8: g_u<1>(st,lane,u00,u01); break;
    case 9: g_u<0>(st,lane,u00,u01); break;
  }
}

#define CRX_CASE(CW,TW) case (CW)*10+(TW): g_crx<9-(TW), 9-(CW)>(st,lane,c,s); break;
__device__ __forceinline__ void crx_w(F2* st, unsigned lane, int cw, int tw, float c, float s) {
  switch (cw * 10 + tw) {
    CRX_CASE(0,1) CRX_CASE(1,2) CRX_CASE(2,3) CRX_CASE(3,4) CRX_CASE(4,5)
    CRX_CASE(5,6) CRX_CASE(6,7) CRX_CASE(7,8) CRX_CASE(8,9) CRX_CASE(9,0)
    CRX_CASE(1,0) CRX_CASE(2,1) CRX_CASE(3,2) CRX_CASE(4,3) CRX_CASE(5,4)
    CRX_CASE(6,5) CRX_CASE(7,6) CRX_CASE(8,7) CRX_CASE(9,8) CRX_CASE(0,9)
  }
}

// U = RZ(az)*RY(ay)*RX(ax) (half-angles inside); SU(2): only u00,u01 needed
__device__ __forceinline__ void make_u(float ax, float ay, float az, F2& u00, F2& u01) {
  float ca, sa, cb, sb, cg, sg;
  __sincosf(ax*0.5f, &sa, &ca);
  __sincosf(ay*0.5f, &sb, &cb);
  __sincosf(az*0.5f, &sg, &cg);
  const float m00x =  cb*ca, m00y =  sb*sa;
  const float m01x = -sb*ca, m01y = -cb*sa;
  u00 = F2{m00x*cg + m00y*sg, m00y*cg - m00x*sg};
  u01 = F2{m01x*cg + m01y*sg, m01y*cg - m01x*sg};
}

// ---------------- circuit layers ----------------

__device__ __forceinline__ void layer_fwd(F2* st, unsigned lane, const float* P, float dt, int& off) {
#pragma unroll
  for (int i = 0; i < NQ; ++i) {
    F2 u00, u01;
    make_u(P[off]*dt, P[off+1]*dt, P[off+2]*dt, u00, u01);
    g_u_w(st, lane, i, u00, u01);
    off += 3;
  }
#pragma unroll
  for (int i = 0; i < NQ; ++i) {
    float s, c; __sincosf(P[off]*0.5f, &s, &c);
    crx_w(st, lane, i, (i+1)%NQ, c, s); ++off;
  }
#pragma unroll
  for (int i = NQ-1; i >= 0; --i) {
    float s, c; __sincosf(P[off]*0.5f, &s, &c);
    crx_w(st, lane, i, (i+NQ-1)%NQ, c, s); ++off;
  }
}

__device__ __forceinline__ void layer_bwd(F2* st, unsigned lane, const float* P, float dt, int& off) {
#pragma unroll
  for (int i = NQ-1; i >= 0; --i) {
    F2 u00, u01;
    make_u(P[off]*dt, P[off+1]*dt, P[off+2]*dt, u00, u01);
    g_u_w(st, lane, i, u00, u01);
    off += 3;
  }
#pragma unroll
  for (int i = NQ-1; i >= 0; --i) {
    float s, c; __sincosf(P[off]*0.5f, &s, &c);
    crx_w(st, lane, i, (i+NQ-1)%NQ, c, s); ++off;
  }
#pragma unroll
  for (int i = 0; i < NQ; ++i) {
    float s, c; __sincosf(P[off]*0.5f, &s, &c);
    crx_w(st, lane, i, (i+1)%NQ, c, s); ++off;
  }
}

// RY-embedded |0..0> is a product state: amp(i) = prod_w (bit_w ? sin : cos)(ang_w/2)
__device__ __forceinline__ void init_state(F2* st, unsigned lane, const float* ang) {
  float cw[NQ], sw[NQ];
#pragma unroll
  for (int w = 0; w < NQ; ++w) __sincosf(ang[w]*0.5f, &sw[w], &cw[w]);
  float L = 1.0f;
#pragma unroll
  for (int q = 0; q < 6; ++q)            // lane bit q <-> wire 5-q
    L *= ((lane >> q) & 1u) ? sw[5-q] : cw[5-q];
#pragma unroll
  for (int r = 0; r < 16; ++r) {
    float R = L;
#pragma unroll
    for (int p = 0; p < 4; ++p)          // reg bit p <-> wire 9-p
      R *= ((r >> p) & 1) ? sw[9-p] : cw[9-p];
    st[r] = F2{R, 0.0f};
  }
}

// ---------------- measurement ----------------

template<int P>
__device__ __forceinline__ void meas(const F2* st, unsigned lane, float& X, float& Y, float& Z) {
  float cr = 0.f, ci = 0.f, z = 0.f;
  if constexpr (P < 4) {
    constexpr int m = 1 << P;
#pragma unroll
    for (int r = 0; r < 16; ++r) if (!(r & m)) {
      const int r1 = r | m;
      F2 a0 = st[r], a1 = st[r1];
      cr += a0.x*a1.x + a0.y*a1.y;
      ci += a0.x*a1.y - a0.y*a1.x;
      z  += (a0.x*a0.x + a0.y*a0.y) - (a1.x*a1.x + a1.y*a1.y);
    }
    cr *= 2.f; ci *= 2.f;
  } else {
    constexpr int lm = 1 << (P - 4);
    const bool hi = (lane & lm) != 0;
#pragma unroll
    for (int r = 0; r < 16; ++r) {
      float mx = st[r].x, my = st[r].y;
      float ox = lshf<lm>(mx), oy = lshf<lm>(my);
      float a0x = hi ? ox : mx, a0y = hi ? oy : my;
      float a1x = hi ? mx : ox, a1y = hi ? my : oy;
      cr += a0x*a1x + a0y*a1y;            // pair counted twice across lanes -> no *2
      ci += a0x*a1y - a0y*a1x;
      float p2 = mx*mx + my*my;
      z += hi ? -p2 : p2;
    }
  }
  X = cr; Y = ci; Z = z;
}

__device__ __forceinline__ float wred(float v) {
  v += lshf<1>(v);
  v += lshf<2>(v);
  v += lshf<4>(v);
  v += lshf<8>(v);
  v += lshf<16>(v);
  v += lshf<32>(v);
  return v;
}

// ---------------- kernel: one wave per batch element (R3 champion structure) ----------------

__global__ void __launch_bounds__(256) qsim_kernel(
    const float* __restrict__ angles, const float* __restrict__ fwdP,
    const float* __restrict__ bwdP,   const float* __restrict__ diagP,
    const float* __restrict__ dts,
    const float* __restrict__ ar, const float* __restrict__ ai,
    const float* __restrict__ br, const float* __restrict__ bi,
    const float* __restrict__ gr, const float* __restrict__ gi,
    float* __restrict__ out)
{
  const int tid = blockIdx.x * blockDim.x + threadIdx.x;
  const int b = tid >> 6;
  if (b >= NBATCH) return;
  const unsigned lane = threadIdx.x & 63u;
  const int bu = __builtin_amdgcn_readfirstlane(b);   // wave-uniform -> scalar addressing

  const float* ang = angles + bu * NQ;
  const float dt = dts[bu];

  const float arv = ar[0], aiv = ai[0], brv = br[0], biv = bi[0], grv = gr[0], giv = gi[0];
  const float nrm = sqrtf(arv*arv + aiv*aiv + brv*brv + biv*biv + grv*grv + giv*giv + 1e-9f);
  const F2 cA{arv/nrm, aiv/nrm}, cB{brv/nrm, biv/nrm}, cG{grv/nrm, giv/nrm};

  F2 st[16], acc[16];

  // circuit 1: forward (params scaled by dt)
  init_state(st, lane, ang);
  { int off = 0; const float* P = fwdP + bu*NPRM;
#pragma unroll
    for (int l = 0; l < 2; ++l) layer_fwd(st, lane, P, dt, off); }
#pragma unroll
  for (int r = 0; r < 16; ++r)
    acc[r] = F2{cA.x*st[r].x - cA.y*st[r].y, cA.x*st[r].y + cA.y*st[r].x};

  // circuit 2: backward
  init_state(st, lane, ang);
  { int off = 0; const float* P = bwdP + bu*NPRM;
#pragma unroll
    for (int l = 0; l < 2; ++l) layer_bwd(st, lane, P, dt, off); }
#pragma unroll
  for (int r = 0; r < 16; ++r) {
    acc[r].x += cB.x*st[r].x - cB.y*st[r].y;
    acc[r].y += cB.x*st[r].y + cB.y*st[r].x;
  }

  // circuit 3: diagonal (forward structure, dt = 1)
  init_state(st, lane, ang);
  { int off = 0; const float* P = diagP + bu*NPRM;
#pragma unroll
    for (int l = 0; l < 2; ++l) layer_fwd(st, lane, P, 1.0f, off); }
#pragma unroll
  for (int r = 0; r < 16; ++r) {
    acc[r].x += cG.x*st[r].x - cG.y*st[r].y;
    acc[r].y += cG.x*st[r].y + cG.y*st[r].x;
  }

  // global normalize
  float n2 = 0.f;
#pragma unroll
  for (int r = 0; r < 16; ++r) n2 += acc[r].x*acc[r].x + acc[r].y*acc[r].y;
  n2 = wred(n2);
  const float inv = 1.0f / (sqrtf(n2) + 1e-9f);
#pragma unroll
  for (int r = 0; r < 16; ++r) { acc[r].x *= inv; acc[r].y *= inv; }

  // measure X/Y/Z per wire
  float* o = out + b * 30;
#pragma unroll
  for (int w = 0; w < NQ; ++w) {
    float X, Y, Z;
    switch (w) {
      case 0: meas<9>(acc, lane, X, Y, Z); break;
      case 1: meas<8>(acc, lane, X, Y, Z); break;
      case 2: meas<7>(acc, lane, X, Y, Z); break;
      case 3: meas<6>(acc, lane, X, Y, Z); break;
      case 4: meas<5>(acc, lane, X, Y, Z); break;
      case 5: meas<4>(acc, lane, X, Y, Z); break;
      case 6: meas<3>(acc, lane, X, Y, Z); break;
      case 7: meas<2>(acc, lane, X, Y, Z); break;
      case 8: meas<1>(acc, lane, X, Y, Z); break;
      default: meas<0>(acc, lane, X, Y, Z); break;
    }
    X = wred(X); Y = wred(Y); Z = wred(Z);
    if (lane == 0) { o[w] = X; o[10 + w] = Y; o[20 + w] = Z; }
  }
}

extern "C" void kernel_launch(void* const* d_in, const int* in_sizes, int n_in,
                              void* d_out, int out_size, void* d_ws, size_t ws_size,
                              hipStream_t stream) {
  const float* angles = (const float*)d_in[0];
  const float* fwdP   = (const float*)d_in[1];
  const float* bwdP   = (const float*)d_in[2];
  const float* diagP  = (const float*)d_in[3];
  const float* dts    = (const float*)d_in[4];
  const float* ar     = (const float*)d_in[5];
  const float* ai     = (const float*)d_in[6];
  const float* br     = (const float*)d_in[7];
  const float* bi     = (const float*)d_in[8];
  const float* gr     = (const float*)d_in[9];
  const float* gi     = (const float*)d_in[10];
  float* out = (float*)d_out;

  const int threads = 256;                       // 4 waves/block, 1 batch elem/wave
  const int blocks  = NBATCH / (threads / 64);   // 2048
  qsim_kernel<<<blocks, threads, 0, stream>>>(
      angles, fwdP, bwdP, diagP, dts, ar, ai, br, bi, gr, gi, out);
}